// Round 10
// baseline (260.405 us; speedup 1.0000x reference)
//
#include <hip/hip_runtime.h>
#include <hip/hip_bf16.h>

#define D_MODEL 1024
#define NH 16
#define HD 64
#define BATCH 2
#define SEQ 2048

typedef __attribute__((ext_vector_type(8))) short short8;
typedef __attribute__((ext_vector_type(4))) float floatx4;

static __device__ __forceinline__ short f2bf(float f) {
    __hip_bfloat16 h = __float2bfloat16(f);
    return *reinterpret_cast<short*>(&h);
}
static __device__ __forceinline__ unsigned int pk2bf(float a, float b) {
    float2 t; t.x = a; t.y = b;
    __hip_bfloat162 h2 = __float22bfloat162_rn(t);
    return *reinterpret_cast<unsigned int*>(&h2);
}

// ---------------------------------------------------------------------------
// fused fp32 -> bf16 convert: x (4M), w_qkv (3M), w_fc (1M)
// ---------------------------------------------------------------------------
__global__ __launch_bounds__(256) void cvt_all(
    const float* __restrict__ x, const float* __restrict__ wq,
    const float* __restrict__ wf,
    short* __restrict__ Xb, short* __restrict__ Wqb, short* __restrict__ Wfb)
{
    int i = blockIdx.x * 256 + threadIdx.x;
    const float* src; short* dst; int off;
    if (i < 524288)      { src = x;  dst = Xb;  off = i; }
    else if (i < 917504) { src = wq; dst = Wqb; off = i - 524288; }
    else                 { src = wf; dst = Wfb; off = i - 917504; }
    float4 a = *reinterpret_cast<const float4*>(src + off * 8);
    float4 b = *reinterpret_cast<const float4*>(src + off * 8 + 4);
    short8 o;
    o[0] = f2bf(a.x); o[1] = f2bf(a.y); o[2] = f2bf(a.z); o[3] = f2bf(a.w);
    o[4] = f2bf(b.x); o[5] = f2bf(b.y); o[6] = f2bf(b.z); o[7] = f2bf(b.w);
    *reinterpret_cast<short8*>(dst + off * 8) = o;
}

// ---------------------------------------------------------------------------
// GEMM1: QKV projection. 128m x 64n pure-type tiles.
// Q scaled by 0.125*log2(e) (softmax uses exp2); K -> [b,h,s,d]; V -> [b,h,d,s].
// ---------------------------------------------------------------------------
__global__ __launch_bounds__(256) void qkv_gemm(
    const short* __restrict__ X, const short* __restrict__ W,
    const float* __restrict__ bias,
    short* __restrict__ Qs, short* __restrict__ Ks, short* __restrict__ Vt_g)
{
    __shared__ __align__(16) short As[128][72];
    __shared__ __align__(16) short Bs[64][72];
    const int tid = threadIdx.x;
    const int bx = blockIdx.x;
    const int m0 = blockIdx.y * 128;
    const int n0 = bx * 64;
    const int h = bx / 3, t = bx % 3;
    const int bi = m0 >> 11;
    const int sl0 = m0 & 2047;
    const int w = tid >> 6, lane = tid & 63;
    const int quad = lane >> 4, l15 = lane & 15;
    const int wm2 = w >> 1, wn2 = w & 1;

    floatx4 acc[4][2];
#pragma unroll
    for (int i = 0; i < 4; i++)
#pragma unroll
        for (int j = 0; j < 2; j++) acc[i][j] = (floatx4)0.0f;

    for (int k0 = 0; k0 < 1024; k0 += 64) {
        __syncthreads();
#pragma unroll
        for (int i = 0; i < 4; i++) {
            int c = tid + i * 256;
            int row = c >> 3, ck = c & 7;
            *reinterpret_cast<uint4*>(&As[row][ck * 8]) =
                *reinterpret_cast<const uint4*>(&X[(m0 + row) * 1024 + k0 + ck * 8]);
        }
#pragma unroll
        for (int i = 0; i < 2; i++) {
            int c = tid + i * 256;
            int row = c >> 3, ck = c & 7;
            *reinterpret_cast<uint4*>(&Bs[row][ck * 8]) =
                *reinterpret_cast<const uint4*>(&W[(n0 + row) * 1024 + k0 + ck * 8]);
        }
        __syncthreads();
#pragma unroll
        for (int kk = 0; kk < 2; kk++) {
            short8 a[4], b[2];
#pragma unroll
            for (int i = 0; i < 4; i++)
                a[i] = *reinterpret_cast<const short8*>(&As[wm2 * 64 + i * 16 + l15][kk * 32 + quad * 8]);
#pragma unroll
            for (int j = 0; j < 2; j++)
                b[j] = *reinterpret_cast<const short8*>(&Bs[wn2 * 32 + j * 16 + l15][kk * 32 + quad * 8]);
#pragma unroll
            for (int mt = 0; mt < 4; mt++)
#pragma unroll
                for (int nt = 0; nt < 2; nt++)
                    acc[mt][nt] = __builtin_amdgcn_mfma_f32_16x16x32_bf16(
                        a[mt], b[nt], acc[mt][nt], 0, 0, 0);
        }
    }

    __syncthreads();
    short* T = &As[0][0];                 // V path: [64 d][136 m] view
#pragma unroll
    for (int nt = 0; nt < 2; nt++) {
        int col = wn2 * 32 + nt * 16 + l15;
        float bv = bias[h * 192 + t * 64 + col];
#pragma unroll
        for (int mt = 0; mt < 4; mt++) {
#pragma unroll
            for (int r = 0; r < 4; r++) {
                int ml = wm2 * 64 + mt * 16 + quad * 4 + r;
                float v = acc[mt][nt][r] + bv;
                if (t == 0) v *= 0.18033688f;   // 0.125 * log2(e)
                if (t < 2) As[ml][col] = f2bf(v);
                else       T[col * 136 + ml] = f2bf(v);
            }
        }
    }
    __syncthreads();

    if (t < 2) {
        short* dst = (t == 0) ? Qs : Ks;
#pragma unroll
        for (int i = 0; i < 4; i++) {
            int c = tid + i * 256;
            int row = c >> 3, ck = c & 7;
            uint4 u = *reinterpret_cast<const uint4*>(&As[row][ck * 8]);
            *reinterpret_cast<uint4*>(
                &dst[((size_t)(bi * NH + h) * SEQ + sl0 + row) * HD + ck * 8]) = u;
        }
    } else {
#pragma unroll
        for (int i = 0; i < 4; i++) {
            int c = tid + i * 256;
            int drow = c >> 4, ck = c & 15;
            uint4 u = *reinterpret_cast<const uint4*>(&T[drow * 136 + ck * 8]);
            *reinterpret_cast<uint4*>(
                &Vt_g[((size_t)(bi * NH + h) * HD + drow) * SEQ + sl0 + ck * 8]) = u;
        }
    }
}

// ---------------------------------------------------------------------------
// Flash attention, barrier-free: K/V MFMA fragments loaded DIRECTLY from
// global (L2-served; XCD-swizzled block->head mapping keeps working set
// ~2MB/XCD). Only per-wave P goes through LDS (wave-local fence). Waves are
// fully independent: no __syncthreads in the kernel.
// Wave = 32 q-rows; block = 4 waves = 128 q. Software-pipelined K/V prefetch.
// ---------------------------------------------------------------------------
__global__ __launch_bounds__(256) void attn_kernel(
    const short* __restrict__ Qs, const short* __restrict__ Ks,
    const short* __restrict__ Vt_g, short* __restrict__ attn)
{
    __shared__ __align__(16) short Pl[4][32][72];  // per-wave P [q_local][k]
    __shared__ float Ls[128];

    const int tid = threadIdx.x;
    const int w = tid >> 6, lane = tid & 63;
    const int quad = lane >> 4, l15 = lane & 15;
    const int j = blockIdx.x;
    // XCD swizzle: dispatch round-robins blockIdx over 8 XCDs -> pin 4 heads/XCD
    const int bh = (j & 7) * 4 + ((j >> 3) & 3);
    const int q0 = (j >> 5) * 128;
    const int bi = bh >> 4, h = bh & 15;
    const int kbase = bh * SEQ * HD;       // K/Q: [s][d]
    const int vbase = bh * HD * SEQ;       // V^T: [d][s]

    // Q B-frags for this wave's 32 q (pre-scaled by 0.125*log2e)
    short8 aq[2][2];
#pragma unroll
    for (int qt2 = 0; qt2 < 2; qt2++) {
        const short* qp = Qs + kbase + (q0 + w * 32 + qt2 * 16 + l15) * HD;
#pragma unroll
        for (int c = 0; c < 2; c++)
            aq[qt2][c] = *reinterpret_cast<const short8*>(qp + c * 32 + quad * 8);
    }

    // K frag base: row l15, 16B chunk quad; V^T frag base: d-row l15, k-chunk quad
    const short* kp = Ks + kbase + l15 * HD + quad * 8;
    const short* vp = Vt_g + vbase + l15 * SEQ + quad * 8;

    short8 kf[8], vf[8];   // [kt2*2+c], [nt*2+c]
#pragma unroll
    for (int kt2 = 0; kt2 < 4; kt2++)
#pragma unroll
        for (int c = 0; c < 2; c++)
            kf[kt2 * 2 + c] = *reinterpret_cast<const short8*>(kp + kt2 * 16 * HD + c * 32);
#pragma unroll
    for (int nt = 0; nt < 4; nt++)
#pragma unroll
        for (int c = 0; c < 2; c++)
            vf[nt * 2 + c] = *reinterpret_cast<const short8*>(vp + nt * 16 * SEQ + c * 32);

    float l_acc[2] = {0.f, 0.f};
    floatx4 o[2][4];
#pragma unroll
    for (int mt = 0; mt < 2; mt++)
#pragma unroll
        for (int nt = 0; nt < 4; nt++) o[mt][nt] = (floatx4)0.0f;

    for (int kt = 0; kt < SEQ; kt += 64) {
        // S^T = K x Q^T : lane holds k = kt2*16+quad*4+r (consecutive), q = l15
        floatx4 sf[4][2];
#pragma unroll
        for (int kt2 = 0; kt2 < 4; kt2++)
#pragma unroll
            for (int qt2 = 0; qt2 < 2; qt2++) sf[kt2][qt2] = (floatx4)0.0f;
#pragma unroll
        for (int c = 0; c < 2; c++)
#pragma unroll
            for (int kt2 = 0; kt2 < 4; kt2++)
#pragma unroll
                for (int qt2 = 0; qt2 < 2; qt2++)
                    sf[kt2][qt2] = __builtin_amdgcn_mfma_f32_16x16x32_bf16(
                        kf[kt2 * 2 + c], aq[qt2][c], sf[kt2][qt2], 0, 0, 0);

        // p = exp2(s') (log2e pre-folded); pack pairs; b64 P writes
#pragma unroll
        for (int kt2 = 0; kt2 < 4; kt2++) {
#pragma unroll
            for (int qt2 = 0; qt2 < 2; qt2++) {
                float e0 = exp2f(sf[kt2][qt2][0]);
                float e1 = exp2f(sf[kt2][qt2][1]);
                float e2 = exp2f(sf[kt2][qt2][2]);
                float e3 = exp2f(sf[kt2][qt2][3]);
                l_acc[qt2] += (e0 + e1) + (e2 + e3);
                uint2 p;
                p.x = pk2bf(e0, e1);
                p.y = pk2bf(e2, e3);
                *reinterpret_cast<uint2*>(&Pl[w][qt2 * 16 + l15][kt2 * 16 + quad * 4]) = p;
            }
        }
        asm volatile("s_waitcnt lgkmcnt(0)" ::: "memory");  // wave-local Pl fence

        // prefetch next K tile (kf consumed by QK above; WAR safe in-order)
        if (kt + 64 < SEQ) {
            const short* kpn = kp + (kt + 64) * HD;
#pragma unroll
            for (int kt2 = 0; kt2 < 4; kt2++)
#pragma unroll
                for (int c = 0; c < 2; c++)
                    kf[kt2 * 2 + c] = *reinterpret_cast<const short8*>(kpn + kt2 * 16 * HD + c * 32);
        }

        // O += P V
#pragma unroll
        for (int c = 0; c < 2; c++) {
#pragma unroll
            for (int mt = 0; mt < 2; mt++) {
                short8 ap = *reinterpret_cast<const short8*>(
                    &Pl[w][mt * 16 + l15][c * 32 + quad * 8]);
#pragma unroll
                for (int nt = 0; nt < 4; nt++)
                    o[mt][nt] = __builtin_amdgcn_mfma_f32_16x16x32_bf16(
                        ap, vf[nt * 2 + c], o[mt][nt], 0, 0, 0);
            }
        }

        // prefetch next V tile
        if (kt + 64 < SEQ) {
            const short* vpn = vp + (kt + 64);
#pragma unroll
            for (int nt = 0; nt < 4; nt++)
#pragma unroll
                for (int c = 0; c < 2; c++)
                    vf[nt * 2 + c] = *reinterpret_cast<const short8*>(vpn + nt * 16 * SEQ + c * 32);
        }
    }

    // finalize l (4 quad partials per q), publish via wave-local LDS
#pragma unroll
    for (int qt2 = 0; qt2 < 2; qt2++) {
        l_acc[qt2] += __shfl_xor(l_acc[qt2], 16);
        l_acc[qt2] += __shfl_xor(l_acc[qt2], 32);
    }
    if (quad == 0) {
        Ls[w * 32 + l15] = l_acc[0];
        Ls[w * 32 + 16 + l15] = l_acc[1];
    }
    asm volatile("s_waitcnt lgkmcnt(0)" ::: "memory");  // wave-local Ls fence

#pragma unroll
    for (int mt = 0; mt < 2; mt++) {
#pragma unroll
        for (int r = 0; r < 4; r++) {
            int ql = w * 32 + mt * 16 + quad * 4 + r;
            float lt = Ls[ql];
#pragma unroll
            for (int nt = 0; nt < 4; nt++) {
                attn[(bi * SEQ + q0 + ql) * D_MODEL + h * HD + nt * 16 + l15] =
                    f2bf(o[mt][nt][r] / lt);
            }
        }
    }
}

// ---------------------------------------------------------------------------
// GEMM2: 128m x 64n tiles -> 512 blocks. fp32 coalesced stores.
// ---------------------------------------------------------------------------
__global__ __launch_bounds__(256) void fc_gemm(
    const short* __restrict__ A, const short* __restrict__ W,
    const float* __restrict__ bias, float* __restrict__ out)
{
    __shared__ __align__(16) short As[128][72];
    __shared__ __align__(16) short Bs[64][72];
    const int tid = threadIdx.x;
    const int m0 = blockIdx.y * 128;
    const int n0 = blockIdx.x * 64;
    const int w = tid >> 6, lane = tid & 63;
    const int quad = lane >> 4, l15 = lane & 15;
    const int wm2 = w >> 1, wn2 = w & 1;

    floatx4 acc[4][2];
#pragma unroll
    for (int i = 0; i < 4; i++)
#pragma unroll
        for (int j = 0; j < 2; j++) acc[i][j] = (floatx4)0.0f;

    for (int k0 = 0; k0 < 1024; k0 += 64) {
        __syncthreads();
#pragma unroll
        for (int i = 0; i < 4; i++) {
            int c = tid + i * 256;
            int row = c >> 3, ck = c & 7;
            *reinterpret_cast<uint4*>(&As[row][ck * 8]) =
                *reinterpret_cast<const uint4*>(&A[(m0 + row) * 1024 + k0 + ck * 8]);
        }
#pragma unroll
        for (int i = 0; i < 2; i++) {
            int c = tid + i * 256;
            int row = c >> 3, ck = c & 7;
            *reinterpret_cast<uint4*>(&Bs[row][ck * 8]) =
                *reinterpret_cast<const uint4*>(&W[(n0 + row) * 1024 + k0 + ck * 8]);
        }
        __syncthreads();
#pragma unroll
        for (int kk = 0; kk < 2; kk++) {
            short8 a[4], b[2];
#pragma unroll
            for (int i = 0; i < 4; i++)
                a[i] = *reinterpret_cast<const short8*>(&As[wm2 * 64 + i * 16 + l15][kk * 32 + quad * 8]);
#pragma unroll
            for (int j = 0; j < 2; j++)
                b[j] = *reinterpret_cast<const short8*>(&Bs[wn2 * 32 + j * 16 + l15][kk * 32 + quad * 8]);
#pragma unroll
            for (int mt = 0; mt < 4; mt++)
#pragma unroll
                for (int nt = 0; nt < 2; nt++)
                    acc[mt][nt] = __builtin_amdgcn_mfma_f32_16x16x32_bf16(
                        a[mt], b[nt], acc[mt][nt], 0, 0, 0);
        }
    }

#pragma unroll
    for (int nt = 0; nt < 2; nt++) {
        int col = n0 + wn2 * 32 + nt * 16 + l15;
        float bv = bias[col];
#pragma unroll
        for (int mt = 0; mt < 4; mt++) {
#pragma unroll
            for (int r = 0; r < 4; r++) {
                int row = m0 + wm2 * 64 + mt * 16 + quad * 4 + r;
                out[row * 1024 + col] = acc[mt][nt][r] + bv;
            }
        }
    }
}

extern "C" void kernel_launch(void* const* d_in, const int* in_sizes, int n_in,
                              void* d_out, int out_size, void* d_ws, size_t ws_size,
                              hipStream_t stream) {
    const float* x     = (const float*)d_in[0];
    const float* w_qkv = (const float*)d_in[1];
    const float* b_qkv = (const float*)d_in[2];
    const float* w_fc  = (const float*)d_in[3];
    const float* b_fc  = (const float*)d_in[4];
    float* out = (float*)d_out;

    const size_t M4 = 4u * 1024 * 1024;
    short* Xb    = (short*)d_ws;
    short* Wqb   = Xb + M4;
    short* Wfb   = Wqb + 3u * 1024 * 1024;
    short* Qs    = Wfb + 1024 * 1024;
    short* Ks    = Qs + M4;
    short* Vt_g  = Ks + M4;
    short* attnb = Xb;                    // alias: Xb dead after qkv_gemm

    cvt_all<<<4096, 256, 0, stream>>>(x, w_qkv, w_fc, Xb, Wqb, Wfb);
    qkv_gemm<<<dim3(48, 32), 256, 0, stream>>>(Xb, Wqb, b_qkv, Qs, Ks, Vt_g);
    attn_kernel<<<512, 256, 0, stream>>>(Qs, Ks, Vt_g, attnb);
    fc_gemm<<<dim3(16, 32), 256, 0, stream>>>(attnb, Wfb, b_fc, out);
}

// Round 12
// 228.897 us; speedup vs baseline: 1.1376x; 1.1376x over previous
//
#include <hip/hip_runtime.h>
#include <hip/hip_bf16.h>

#define D_MODEL 1024
#define NH 16
#define HD 64
#define BATCH 2
#define SEQ 2048

typedef __attribute__((ext_vector_type(8))) short short8;
typedef __attribute__((ext_vector_type(4))) float floatx4;

static __device__ __forceinline__ short f2bf(float f) {
    __hip_bfloat16 h = __float2bfloat16(f);
    return *reinterpret_cast<short*>(&h);
}
static __device__ __forceinline__ unsigned int pk2bf(float a, float b) {
    float2 t; t.x = a; t.y = b;
    __hip_bfloat162 h2 = __float22bfloat162_rn(t);
    return *reinterpret_cast<unsigned int*>(&h2);
}

// ---------------------------------------------------------------------------
// fused fp32 -> bf16 convert: x (4M), w_qkv (3M), w_fc (1M)
// ---------------------------------------------------------------------------
__global__ __launch_bounds__(256) void cvt_all(
    const float* __restrict__ x, const float* __restrict__ wq,
    const float* __restrict__ wf,
    short* __restrict__ Xb, short* __restrict__ Wqb, short* __restrict__ Wfb)
{
    int i = blockIdx.x * 256 + threadIdx.x;
    const float* src; short* dst; int off;
    if (i < 524288)      { src = x;  dst = Xb;  off = i; }
    else if (i < 917504) { src = wq; dst = Wqb; off = i - 524288; }
    else                 { src = wf; dst = Wfb; off = i - 917504; }
    float4 a = *reinterpret_cast<const float4*>(src + off * 8);
    float4 b = *reinterpret_cast<const float4*>(src + off * 8 + 4);
    short8 o;
    o[0] = f2bf(a.x); o[1] = f2bf(a.y); o[2] = f2bf(a.z); o[3] = f2bf(a.w);
    o[4] = f2bf(b.x); o[5] = f2bf(b.y); o[6] = f2bf(b.z); o[7] = f2bf(b.w);
    *reinterpret_cast<short8*>(dst + off * 8) = o;
}

// ---------------------------------------------------------------------------
// GEMM1: QKV projection, 128x128 tiles (32 MFMA/wave/stage). Each 64-col half
// of a tile is pure-type (64 | gcd(128,192)): epilogue bounces each half
// through LDS (transposed for V) -> coalesced dwordx4 stores.
// Q scaled by 0.125*log2(e); K -> [b,h,s,d]; V -> [b,h,d,s].
// ---------------------------------------------------------------------------
__global__ __launch_bounds__(256) void qkv_gemm(
    const short* __restrict__ X, const short* __restrict__ W,
    const float* __restrict__ bias,
    short* __restrict__ Qs, short* __restrict__ Ks, short* __restrict__ Vt_g)
{
    __shared__ __align__(16) short As[128][72];
    __shared__ __align__(16) short Bs[128][72];
    const int tid = threadIdx.x;
    const int m0 = blockIdx.y * 128;
    const int n0 = blockIdx.x * 128;
    const int bi = m0 >> 11, sl0 = m0 & 2047;
    const int w = tid >> 6, lane = tid & 63;
    const int quad = lane >> 4, l15 = lane & 15;
    const int wm2 = w >> 1, wn2 = w & 1;

    floatx4 acc[4][4];
#pragma unroll
    for (int i = 0; i < 4; i++)
#pragma unroll
        for (int j = 0; j < 4; j++) acc[i][j] = (floatx4)0.0f;

    for (int k0 = 0; k0 < 1024; k0 += 64) {
        __syncthreads();
#pragma unroll
        for (int i = 0; i < 4; i++) {
            int c = tid + i * 256;
            int row = c >> 3, ck = c & 7;
            *reinterpret_cast<uint4*>(&As[row][ck * 8]) =
                *reinterpret_cast<const uint4*>(&X[(m0 + row) * 1024 + k0 + ck * 8]);
            *reinterpret_cast<uint4*>(&Bs[row][ck * 8]) =
                *reinterpret_cast<const uint4*>(&W[(n0 + row) * 1024 + k0 + ck * 8]);
        }
        __syncthreads();
#pragma unroll
        for (int kk = 0; kk < 2; kk++) {
            short8 a[4], b[4];
#pragma unroll
            for (int t = 0; t < 4; t++) {
                a[t] = *reinterpret_cast<const short8*>(&As[wm2 * 64 + t * 16 + l15][kk * 32 + quad * 8]);
                b[t] = *reinterpret_cast<const short8*>(&Bs[wn2 * 64 + t * 16 + l15][kk * 32 + quad * 8]);
            }
#pragma unroll
            for (int mt = 0; mt < 4; mt++)
#pragma unroll
                for (int nt = 0; nt < 4; nt++)
                    acc[mt][nt] = __builtin_amdgcn_mfma_f32_16x16x32_bf16(
                        a[mt], b[nt], acc[mt][nt], 0, 0, 0);
        }
    }

    __syncthreads();   // MFMA LDS reads done; As reusable
    short* T = &As[0][0];   // transposed view [64 d][136 m] for V halves
#pragma unroll
    for (int half = 0; half < 2; half++) {
        const int colg0 = n0 + half * 64;
        const int h = colg0 / 192;
        const int t = (colg0 % 192) / 64;
        if (wn2 == half) {
#pragma unroll
            for (int nt = 0; nt < 4; nt++) {
                int jj = nt * 16 + l15;
                float bv = bias[colg0 + jj];
#pragma unroll
                for (int mt = 0; mt < 4; mt++) {
#pragma unroll
                    for (int r = 0; r < 4; r++) {
                        int ml = wm2 * 64 + mt * 16 + quad * 4 + r;
                        float v = acc[mt][nt][r] + bv;
                        if (t == 0) v *= 0.18033688f;   // 0.125 * log2(e)
                        if (t < 2) As[ml][jj] = f2bf(v);
                        else       T[jj * 136 + ml] = f2bf(v);
                    }
                }
            }
        }
        __syncthreads();
        if (t < 2) {
            short* dst = (t == 0) ? Qs : Ks;
#pragma unroll
            for (int i = 0; i < 4; i++) {       // 128 rows x 8 chunks = 64 cols
                int c = tid + i * 256;
                int row = c >> 3, ck = c & 7;
                uint4 u = *reinterpret_cast<const uint4*>(&As[row][ck * 8]);
                *reinterpret_cast<uint4*>(
                    &dst[((size_t)(bi * NH + h) * SEQ + sl0 + row) * HD + ck * 8]) = u;
            }
        } else {
#pragma unroll
            for (int i = 0; i < 4; i++) {       // 64 d-rows x 16 chunks = 128 m
                int c = tid + i * 256;
                int d = c >> 4, ck = c & 15;
                uint4 u = *reinterpret_cast<const uint4*>(&T[d * 136 + ck * 8]);
                *reinterpret_cast<uint4*>(
                    &Vt_g[((size_t)(bi * NH + h) * HD + d) * SEQ + sl0 + ck * 8]) = u;
            }
        }
        __syncthreads();   // As free for next half
    }
}

// ---------------------------------------------------------------------------
// Flash attention, softmax-lite, DOUBLE-BUFFERED K/V staging:
// one barrier/tile; next tile's global loads issue right after the barrier
// and land in LDS after compute -> load latency overlaps QK/exp/PV.
// Block = 128 q (4 waves x 32 q, each wave spans full 64-k tile).
// ---------------------------------------------------------------------------
__global__ __launch_bounds__(256) void attn_kernel(
    const short* __restrict__ Qs, const short* __restrict__ Ks,
    const short* __restrict__ Vt_g, short* __restrict__ attn)
{
    __shared__ __align__(16) short Kl[2][64][72];  // [buf][k_local][d]
    __shared__ __align__(16) short Vt[2][64][72];  // [buf][d][k_local]
    __shared__ __align__(16) short Pl[4][32][72];  // per-wave P [q_local][k]
    __shared__ float Ls[128];

    const int tid = threadIdx.x;
    const int w = tid >> 6, lane = tid & 63;
    const int quad = lane >> 4, l15 = lane & 15;
    const int q0 = blockIdx.x * 128;
    const int h = blockIdx.y, bi = blockIdx.z;
    const int bh = bi * NH + h;
    const int kbase = bh * SEQ * HD;       // K/Q: [s][d]
    const int vbase = bh * HD * SEQ;       // V^T: [d][s]

    const int kr0 = tid >> 3,         kc0 = (tid & 7) * 8;
    const int kr1 = (tid + 256) >> 3, kc1 = (tid & 7) * 8;  // rows 32..63

    short8 aq[2][2];
#pragma unroll
    for (int qt2 = 0; qt2 < 2; qt2++) {
        const short* qp = Qs + kbase + (q0 + w * 32 + qt2 * 16 + l15) * HD;
#pragma unroll
        for (int c = 0; c < 2; c++)
            aq[qt2][c] = *reinterpret_cast<const short8*>(qp + c * 32 + quad * 8);
    }

    {
        uint4 ka = *reinterpret_cast<const uint4*>(&Ks[kbase + kr0 * HD + kc0]);
        uint4 kb = *reinterpret_cast<const uint4*>(&Ks[kbase + kr1 * HD + kc1]);
        uint4 va = *reinterpret_cast<const uint4*>(&Vt_g[vbase + kr0 * SEQ + kc0]);
        uint4 vb = *reinterpret_cast<const uint4*>(&Vt_g[vbase + kr1 * SEQ + kc1]);
        *reinterpret_cast<uint4*>(&Kl[0][kr0][kc0]) = ka;
        *reinterpret_cast<uint4*>(&Kl[0][kr1][kc1]) = kb;
        *reinterpret_cast<uint4*>(&Vt[0][kr0][kc0]) = va;
        *reinterpret_cast<uint4*>(&Vt[0][kr1][kc1]) = vb;
    }

    float l_acc[2] = {0.f, 0.f};
    floatx4 o[2][4];
#pragma unroll
    for (int mt = 0; mt < 2; mt++)
#pragma unroll
        for (int nt = 0; nt < 4; nt++) o[mt][nt] = (floatx4)0.0f;

    for (int it = 0; it < SEQ / 64; it++) {
        const int cur = it & 1;
        __syncthreads();

        uint4 kna, knb, vna, vnb;
        const bool more = (it + 1 < SEQ / 64);
        if (more) {
            int ktn = (it + 1) * 64;
            kna = *reinterpret_cast<const uint4*>(&Ks[kbase + (ktn + kr0) * HD + kc0]);
            knb = *reinterpret_cast<const uint4*>(&Ks[kbase + (ktn + kr1) * HD + kc1]);
            vna = *reinterpret_cast<const uint4*>(&Vt_g[vbase + kr0 * SEQ + ktn + kc0]);
            vnb = *reinterpret_cast<const uint4*>(&Vt_g[vbase + kr1 * SEQ + ktn + kc1]);
        }

        floatx4 sf[4][2];
#pragma unroll
        for (int kt2 = 0; kt2 < 4; kt2++)
#pragma unroll
            for (int qt2 = 0; qt2 < 2; qt2++) sf[kt2][qt2] = (floatx4)0.0f;
#pragma unroll
        for (int c = 0; c < 2; c++) {
#pragma unroll
            for (int kt2 = 0; kt2 < 4; kt2++) {
                short8 bk = *reinterpret_cast<const short8*>(
                    &Kl[cur][kt2 * 16 + l15][c * 32 + quad * 8]);
#pragma unroll
                for (int qt2 = 0; qt2 < 2; qt2++)
                    sf[kt2][qt2] = __builtin_amdgcn_mfma_f32_16x16x32_bf16(
                        bk, aq[qt2][c], sf[kt2][qt2], 0, 0, 0);
            }
        }

#pragma unroll
        for (int kt2 = 0; kt2 < 4; kt2++) {
#pragma unroll
            for (int qt2 = 0; qt2 < 2; qt2++) {
                float e0 = exp2f(sf[kt2][qt2][0]);
                float e1 = exp2f(sf[kt2][qt2][1]);
                float e2 = exp2f(sf[kt2][qt2][2]);
                float e3 = exp2f(sf[kt2][qt2][3]);
                l_acc[qt2] += (e0 + e1) + (e2 + e3);
                uint2 p;
                p.x = pk2bf(e0, e1);
                p.y = pk2bf(e2, e3);
                *reinterpret_cast<uint2*>(&Pl[w][qt2 * 16 + l15][kt2 * 16 + quad * 4]) = p;
            }
        }
        asm volatile("s_waitcnt lgkmcnt(0)" ::: "memory");  // wave-local Pl fence

#pragma unroll
        for (int c = 0; c < 2; c++) {
#pragma unroll
            for (int mt = 0; mt < 2; mt++) {
                short8 ap = *reinterpret_cast<const short8*>(
                    &Pl[w][mt * 16 + l15][c * 32 + quad * 8]);
#pragma unroll
                for (int nt = 0; nt < 4; nt++) {
                    short8 bv = *reinterpret_cast<const short8*>(
                        &Vt[cur][nt * 16 + l15][c * 32 + quad * 8]);
                    o[mt][nt] = __builtin_amdgcn_mfma_f32_16x16x32_bf16(
                        ap, bv, o[mt][nt], 0, 0, 0);
                }
            }
        }

        if (more) {
            int nxt = 1 - cur;
            *reinterpret_cast<uint4*>(&Kl[nxt][kr0][kc0]) = kna;
            *reinterpret_cast<uint4*>(&Kl[nxt][kr1][kc1]) = knb;
            *reinterpret_cast<uint4*>(&Vt[nxt][kr0][kc0]) = vna;
            *reinterpret_cast<uint4*>(&Vt[nxt][kr1][kc1]) = vnb;
        }
    }

#pragma unroll
    for (int qt2 = 0; qt2 < 2; qt2++) {
        l_acc[qt2] += __shfl_xor(l_acc[qt2], 16);
        l_acc[qt2] += __shfl_xor(l_acc[qt2], 32);
    }
    if (quad == 0) {
        Ls[w * 32 + l15] = l_acc[0];
        Ls[w * 32 + 16 + l15] = l_acc[1];
    }
    asm volatile("s_waitcnt lgkmcnt(0)" ::: "memory");  // wave-local Ls fence

#pragma unroll
    for (int mt = 0; mt < 2; mt++) {
#pragma unroll
        for (int r = 0; r < 4; r++) {
            int ql = w * 32 + mt * 16 + quad * 4 + r;
            float lt = Ls[ql];
#pragma unroll
            for (int nt = 0; nt < 4; nt++) {
                attn[(bi * SEQ + q0 + ql) * D_MODEL + h * HD + nt * 16 + l15] =
                    f2bf(o[mt][nt][r] / lt);
            }
        }
    }
}

// ---------------------------------------------------------------------------
// GEMM2: 128m x 64n tiles -> 512 blocks. fp32 coalesced stores.
// ---------------------------------------------------------------------------
__global__ __launch_bounds__(256) void fc_gemm(
    const short* __restrict__ A, const short* __restrict__ W,
    const float* __restrict__ bias, float* __restrict__ out)
{
    __shared__ __align__(16) short As[128][72];
    __shared__ __align__(16) short Bs[64][72];
    const int tid = threadIdx.x;
    const int m0 = blockIdx.y * 128;
    const int n0 = blockIdx.x * 64;
    const int w = tid >> 6, lane = tid & 63;
    const int quad = lane >> 4, l15 = lane & 15;
    const int wm2 = w >> 1, wn2 = w & 1;

    floatx4 acc[4][2];
#pragma unroll
    for (int i = 0; i < 4; i++)
#pragma unroll
        for (int j = 0; j < 2; j++) acc[i][j] = (floatx4)0.0f;

    for (int k0 = 0; k0 < 1024; k0 += 64) {
        __syncthreads();
#pragma unroll
        for (int i = 0; i < 4; i++) {
            int c = tid + i * 256;
            int row = c >> 3, ck = c & 7;
            *reinterpret_cast<uint4*>(&As[row][ck * 8]) =
                *reinterpret_cast<const uint4*>(&A[(m0 + row) * 1024 + k0 + ck * 8]);
        }
#pragma unroll
        for (int i = 0; i < 2; i++) {
            int c = tid + i * 256;
            int row = c >> 3, ck = c & 7;
            *reinterpret_cast<uint4*>(&Bs[row][ck * 8]) =
                *reinterpret_cast<const uint4*>(&W[(n0 + row) * 1024 + k0 + ck * 8]);
        }
        __syncthreads();
#pragma unroll
        for (int kk = 0; kk < 2; kk++) {
            short8 a[4], b[2];
#pragma unroll
            for (int i = 0; i < 4; i++)
                a[i] = *reinterpret_cast<const short8*>(&As[wm2 * 64 + i * 16 + l15][kk * 32 + quad * 8]);
#pragma unroll
            for (int j = 0; j < 2; j++)
                b[j] = *reinterpret_cast<const short8*>(&Bs[wn2 * 32 + j * 16 + l15][kk * 32 + quad * 8]);
#pragma unroll
            for (int mt = 0; mt < 4; mt++)
#pragma unroll
                for (int nt = 0; nt < 2; nt++)
                    acc[mt][nt] = __builtin_amdgcn_mfma_f32_16x16x32_bf16(
                        a[mt], b[nt], acc[mt][nt], 0, 0, 0);
        }
    }

#pragma unroll
    for (int nt = 0; nt < 2; nt++) {
        int col = n0 + wn2 * 32 + nt * 16 + l15;
        float bv = bias[col];
#pragma unroll
        for (int mt = 0; mt < 4; mt++) {
#pragma unroll
            for (int r = 0; r < 4; r++) {
                int row = m0 + wm2 * 64 + mt * 16 + quad * 4 + r;
                out[row * 1024 + col] = acc[mt][nt][r] + bv;
            }
        }
    }
}

extern "C" void kernel_launch(void* const* d_in, const int* in_sizes, int n_in,
                              void* d_out, int out_size, void* d_ws, size_t ws_size,
                              hipStream_t stream) {
    const float* x     = (const float*)d_in[0];
    const float* w_qkv = (const float*)d_in[1];
    const float* b_qkv = (const float*)d_in[2];
    const float* w_fc  = (const float*)d_in[3];
    const float* b_fc  = (const float*)d_in[4];
    float* out = (float*)d_out;

    const size_t M4 = 4u * 1024 * 1024;
    short* Xb    = (short*)d_ws;
    short* Wqb   = Xb + M4;
    short* Wfb   = Wqb + 3u * 1024 * 1024;
    short* Qs    = Wfb + 1024 * 1024;
    short* Ks    = Qs + M4;
    short* Vt_g  = Ks + M4;
    short* attnb = Xb;                    // alias: Xb dead after qkv_gemm

    cvt_all<<<4096, 256, 0, stream>>>(x, w_qkv, w_fc, Xb, Wqb, Wfb);
    qkv_gemm<<<dim3(24, 32), 256, 0, stream>>>(Xb, Wqb, b_qkv, Qs, Ks, Vt_g);
    attn_kernel<<<dim3(16, 16, 2), 256, 0, stream>>>(Qs, Ks, Vt_g, attnb);
    fc_gemm<<<dim3(16, 32), 256, 0, stream>>>(attnb, Wfb, b_fc, out);
}

// Round 13
// 222.312 us; speedup vs baseline: 1.1713x; 1.0296x over previous
//
#include <hip/hip_runtime.h>
#include <hip/hip_bf16.h>
#include <hip/hip_fp16.h>

#define D_MODEL 1024
#define NH 16
#define HD 64
#define BATCH 2
#define SEQ 2048

typedef __attribute__((ext_vector_type(8))) short short8;
typedef __attribute__((ext_vector_type(4))) float floatx4;
typedef __attribute__((ext_vector_type(8))) _Float16 half8;

static __device__ __forceinline__ short f2bf(float f) {
    __hip_bfloat16 h = __float2bfloat16(f);
    return *reinterpret_cast<short*>(&h);
}
static __device__ __forceinline__ unsigned int pk2bf(float a, float b) {
    float2 t; t.x = a; t.y = b;
    __hip_bfloat162 h2 = __float22bfloat162_rn(t);
    return *reinterpret_cast<unsigned int*>(&h2);
}

// ---------------------------------------------------------------------------
// fused fp32 -> bf16 convert: x (4M), w_qkv (3M), w_fc (1M)
// ---------------------------------------------------------------------------
__global__ __launch_bounds__(256) void cvt_all(
    const float* __restrict__ x, const float* __restrict__ wq,
    const float* __restrict__ wf,
    short* __restrict__ Xb, short* __restrict__ Wqb, short* __restrict__ Wfb)
{
    int i = blockIdx.x * 256 + threadIdx.x;
    const float* src; short* dst; int off;
    if (i < 524288)      { src = x;  dst = Xb;  off = i; }
    else if (i < 917504) { src = wq; dst = Wqb; off = i - 524288; }
    else                 { src = wf; dst = Wfb; off = i - 917504; }
    float4 a = *reinterpret_cast<const float4*>(src + off * 8);
    float4 b = *reinterpret_cast<const float4*>(src + off * 8 + 4);
    short8 o;
    o[0] = f2bf(a.x); o[1] = f2bf(a.y); o[2] = f2bf(a.z); o[3] = f2bf(a.w);
    o[4] = f2bf(b.x); o[5] = f2bf(b.y); o[6] = f2bf(b.z); o[7] = f2bf(b.w);
    *reinterpret_cast<short8*>(dst + off * 8) = o;
}

// ---------------------------------------------------------------------------
// GEMM1: QKV projection (R12, verified). 128x128 tiles, pure-type 64-halves.
// Q scaled by 0.125*log2(e); K -> [b,h,s,d]; V -> [b,h,d,s].
// ---------------------------------------------------------------------------
__global__ __launch_bounds__(256) void qkv_gemm(
    const short* __restrict__ X, const short* __restrict__ W,
    const float* __restrict__ bias,
    short* __restrict__ Qs, short* __restrict__ Ks, short* __restrict__ Vt_g)
{
    __shared__ __align__(16) short As[128][72];
    __shared__ __align__(16) short Bs[128][72];
    const int tid = threadIdx.x;
    const int m0 = blockIdx.y * 128;
    const int n0 = blockIdx.x * 128;
    const int bi = m0 >> 11, sl0 = m0 & 2047;
    const int w = tid >> 6, lane = tid & 63;
    const int quad = lane >> 4, l15 = lane & 15;
    const int wm2 = w >> 1, wn2 = w & 1;

    floatx4 acc[4][4];
#pragma unroll
    for (int i = 0; i < 4; i++)
#pragma unroll
        for (int j = 0; j < 4; j++) acc[i][j] = (floatx4)0.0f;

    for (int k0 = 0; k0 < 1024; k0 += 64) {
        __syncthreads();
#pragma unroll
        for (int i = 0; i < 4; i++) {
            int c = tid + i * 256;
            int row = c >> 3, ck = c & 7;
            *reinterpret_cast<uint4*>(&As[row][ck * 8]) =
                *reinterpret_cast<const uint4*>(&X[(m0 + row) * 1024 + k0 + ck * 8]);
            *reinterpret_cast<uint4*>(&Bs[row][ck * 8]) =
                *reinterpret_cast<const uint4*>(&W[(n0 + row) * 1024 + k0 + ck * 8]);
        }
        __syncthreads();
#pragma unroll
        for (int kk = 0; kk < 2; kk++) {
            short8 a[4], b[4];
#pragma unroll
            for (int t = 0; t < 4; t++) {
                a[t] = *reinterpret_cast<const short8*>(&As[wm2 * 64 + t * 16 + l15][kk * 32 + quad * 8]);
                b[t] = *reinterpret_cast<const short8*>(&Bs[wn2 * 64 + t * 16 + l15][kk * 32 + quad * 8]);
            }
#pragma unroll
            for (int mt = 0; mt < 4; mt++)
#pragma unroll
                for (int nt = 0; nt < 4; nt++)
                    acc[mt][nt] = __builtin_amdgcn_mfma_f32_16x16x32_bf16(
                        a[mt], b[nt], acc[mt][nt], 0, 0, 0);
        }
    }

    __syncthreads();
    short* T = &As[0][0];
#pragma unroll
    for (int half = 0; half < 2; half++) {
        const int colg0 = n0 + half * 64;
        const int h = colg0 / 192;
        const int t = (colg0 % 192) / 64;
        if (wn2 == half) {
#pragma unroll
            for (int nt = 0; nt < 4; nt++) {
                int jj = nt * 16 + l15;
                float bv = bias[colg0 + jj];
#pragma unroll
                for (int mt = 0; mt < 4; mt++) {
#pragma unroll
                    for (int r = 0; r < 4; r++) {
                        int ml = wm2 * 64 + mt * 16 + quad * 4 + r;
                        float v = acc[mt][nt][r] + bv;
                        if (t == 0) v *= 0.18033688f;   // 0.125 * log2(e)
                        if (t < 2) As[ml][jj] = f2bf(v);
                        else       T[jj * 136 + ml] = f2bf(v);
                    }
                }
            }
        }
        __syncthreads();
        if (t < 2) {
            short* dst = (t == 0) ? Qs : Ks;
#pragma unroll
            for (int i = 0; i < 4; i++) {
                int c = tid + i * 256;
                int row = c >> 3, ck = c & 7;
                uint4 u = *reinterpret_cast<const uint4*>(&As[row][ck * 8]);
                *reinterpret_cast<uint4*>(
                    &dst[((size_t)(bi * NH + h) * SEQ + sl0 + row) * HD + ck * 8]) = u;
            }
        } else {
#pragma unroll
            for (int i = 0; i < 4; i++) {
                int c = tid + i * 256;
                int d = c >> 4, ck = c & 15;
                uint4 u = *reinterpret_cast<const uint4*>(&T[d * 136 + ck * 8]);
                *reinterpret_cast<uint4*>(
                    &Vt_g[((size_t)(bi * NH + h) * HD + d) * SEQ + sl0 + ck * 8]) = u;
            }
        }
        __syncthreads();
    }
}

// ---------------------------------------------------------------------------
// Flash attention, K-SPLIT x2 (softmax-lite partials add exactly):
// block = (128 q, half the keys = 16 tiles); grid 1024 = 4 blocks/CU.
// Single-buffered K/V, hoisted V/P frag reads, l via ones-MFMA.
// Outputs UNnormalized O (fp16) + l (fp32) per half; combined later.
// ---------------------------------------------------------------------------
__global__ __launch_bounds__(256, 4) void attn_kernel(
    const short* __restrict__ Qs, const short* __restrict__ Ks,
    const short* __restrict__ Vt_g,
    _Float16* __restrict__ Opart, float* __restrict__ lpart)
{
    __shared__ __align__(16) short Kl[64][72];     // [k_local][d]
    __shared__ __align__(16) short Vt[64][72];     // [d][k_local]
    __shared__ __align__(16) short Pl[4][32][72];  // per-wave P [q_local][k]

    const int tid = threadIdx.x;
    const int w = tid >> 6, lane = tid & 63;
    const int quad = lane >> 4, l15 = lane & 15;
    const int bx = blockIdx.x;              // 32: qblk = bx>>1, khalf = bx&1
    const int khalf = bx & 1;
    const int q0 = (bx >> 1) * 128;
    const int h = blockIdx.y, bi = blockIdx.z;
    const int bh = bi * NH + h;
    const int kbase = bh * SEQ * HD;        // K/Q: [s][d]
    const int vbase = bh * HD * SEQ;        // V^T: [d][s]
    const int kt0 = khalf * (SEQ / 2);

    const int kr0 = tid >> 3,         kc0 = (tid & 7) * 8;
    const int kr1 = (tid + 256) >> 3, kc1 = (tid & 7) * 8;  // rows 32..63

    const short8 onesv = {(short)0x3F80, (short)0x3F80, (short)0x3F80, (short)0x3F80,
                          (short)0x3F80, (short)0x3F80, (short)0x3F80, (short)0x3F80};

    // Q B-frags for this wave's 32 q (pre-scaled by 0.125*log2e)
    short8 aq[2][2];
#pragma unroll
    for (int qt2 = 0; qt2 < 2; qt2++) {
        const short* qp = Qs + kbase + (q0 + w * 32 + qt2 * 16 + l15) * HD;
#pragma unroll
        for (int c = 0; c < 2; c++)
            aq[qt2][c] = *reinterpret_cast<const short8*>(qp + c * 32 + quad * 8);
    }

    floatx4 o[2][4], ol[2];
#pragma unroll
    for (int mt = 0; mt < 2; mt++) {
        ol[mt] = (floatx4)0.0f;
#pragma unroll
        for (int nt = 0; nt < 4; nt++) o[mt][nt] = (floatx4)0.0f;
    }

    for (int it = 0; it < SEQ / 128; it++) {
        const int kt = kt0 + it * 64;
        __syncthreads();   // previous tile's reads done
        *reinterpret_cast<uint4*>(&Kl[kr0][kc0]) =
            *reinterpret_cast<const uint4*>(&Ks[kbase + (kt + kr0) * HD + kc0]);
        *reinterpret_cast<uint4*>(&Kl[kr1][kc1]) =
            *reinterpret_cast<const uint4*>(&Ks[kbase + (kt + kr1) * HD + kc1]);
        *reinterpret_cast<uint4*>(&Vt[kr0][kc0]) =
            *reinterpret_cast<const uint4*>(&Vt_g[vbase + kr0 * SEQ + kt + kc0]);
        *reinterpret_cast<uint4*>(&Vt[kr1][kc1]) =
            *reinterpret_cast<const uint4*>(&Vt_g[vbase + kr1 * SEQ + kt + kc1]);
        __syncthreads();   // staged

        // S^T (64k x 32q): lane k = kt2*16+quad*4+r (consecutive), q = l15
        floatx4 sf[4][2];
#pragma unroll
        for (int kt2 = 0; kt2 < 4; kt2++)
#pragma unroll
            for (int qt2 = 0; qt2 < 2; qt2++) sf[kt2][qt2] = (floatx4)0.0f;
#pragma unroll
        for (int c = 0; c < 2; c++) {
#pragma unroll
            for (int kt2 = 0; kt2 < 4; kt2++) {
                short8 bk = *reinterpret_cast<const short8*>(
                    &Kl[kt2 * 16 + l15][c * 32 + quad * 8]);
#pragma unroll
                for (int qt2 = 0; qt2 < 2; qt2++)
                    sf[kt2][qt2] = __builtin_amdgcn_mfma_f32_16x16x32_bf16(
                        bk, aq[qt2][c], sf[kt2][qt2], 0, 0, 0);
            }
        }

        // p = exp2(s'); pack consecutive-k pairs; b64 P writes (no l adds)
#pragma unroll
        for (int kt2 = 0; kt2 < 4; kt2++) {
#pragma unroll
            for (int qt2 = 0; qt2 < 2; qt2++) {
                uint2 p;
                p.x = pk2bf(exp2f(sf[kt2][qt2][0]), exp2f(sf[kt2][qt2][1]));
                p.y = pk2bf(exp2f(sf[kt2][qt2][2]), exp2f(sf[kt2][qt2][3]));
                *reinterpret_cast<uint2*>(&Pl[w][qt2 * 16 + l15][kt2 * 16 + quad * 4]) = p;
            }
        }
        asm volatile("s_waitcnt lgkmcnt(0)" ::: "memory");  // wave-local Pl fence

        // O += P V ; l += P * ones  (V/P frags hoisted per c)
#pragma unroll
        for (int c = 0; c < 2; c++) {
            short8 vf[4];
#pragma unroll
            for (int nt = 0; nt < 4; nt++)
                vf[nt] = *reinterpret_cast<const short8*>(
                    &Vt[nt * 16 + l15][c * 32 + quad * 8]);
#pragma unroll
            for (int mt = 0; mt < 2; mt++) {
                short8 ap = *reinterpret_cast<const short8*>(
                    &Pl[w][mt * 16 + l15][c * 32 + quad * 8]);
#pragma unroll
                for (int nt = 0; nt < 4; nt++)
                    o[mt][nt] = __builtin_amdgcn_mfma_f32_16x16x32_bf16(
                        ap, vf[nt], o[mt][nt], 0, 0, 0);
                ol[mt] = __builtin_amdgcn_mfma_f32_16x16x32_bf16(
                    ap, onesv, ol[mt], 0, 0, 0);
            }
        }
    }

    // epilogue: unnormalized fp16 O + fp32 l (per-lane aligned; no shuffles)
#pragma unroll
    for (int mt = 0; mt < 2; mt++) {
#pragma unroll
        for (int r = 0; r < 4; r++) {
            int ql = q0 + w * 32 + mt * 16 + quad * 4 + r;
            size_t base = (size_t)khalf * (4096u * 1024u) +
                          ((size_t)bi * SEQ + ql) * D_MODEL + h * HD;
#pragma unroll
            for (int nt = 0; nt < 4; nt++)
                Opart[base + nt * 16 + l15] = (_Float16)o[mt][nt][r];
            if (l15 == 0)
                lpart[khalf * 65536 + bh * SEQ + ql] = ol[mt][r];
        }
    }
}

// ---------------------------------------------------------------------------
// combine: attnb[m][e] = bf16( (O1+O2)/(l1+l2) ).  8 elems/thread.
// ---------------------------------------------------------------------------
__global__ __launch_bounds__(256) void combine_kernel(
    const _Float16* __restrict__ O, const float* __restrict__ lp,
    short* __restrict__ attnb)
{
    int i = blockIdx.x * 256 + threadIdx.x;   // 524288 threads
    int m = i >> 7;                  // row 0..4095
    int e0 = (i & 127) * 8;          // col chunk (within one head: 8 | 64)
    int bi = m >> 11, s = m & 2047, h = e0 >> 6;
    int bh = bi * NH + h;
    float l = lp[bh * SEQ + s] + lp[65536 + bh * SEQ + s];
    float rl = 1.0f / l;
    size_t off = (size_t)m * D_MODEL + e0;
    half8 a = *reinterpret_cast<const half8*>(O + off);
    half8 b = *reinterpret_cast<const half8*>(O + 4096u * 1024u + off);
    short8 out;
#pragma unroll
    for (int j = 0; j < 8; j++)
        out[j] = f2bf(((float)a[j] + (float)b[j]) * rl);
    *reinterpret_cast<short8*>(attnb + off) = out;
}

// ---------------------------------------------------------------------------
// GEMM2 (unchanged): out[m,e] = sum_k attn[m,k]*Wfc[e,k]+b_fc[e]. fp32 out.
// ---------------------------------------------------------------------------
__global__ __launch_bounds__(256) void fc_gemm(
    const short* __restrict__ A, const short* __restrict__ W,
    const float* __restrict__ bias, float* __restrict__ out)
{
    __shared__ __align__(16) short As[128][72];
    __shared__ __align__(16) short Bs[64][72];
    const int tid = threadIdx.x;
    const int m0 = blockIdx.y * 128;
    const int n0 = blockIdx.x * 64;
    const int w = tid >> 6, lane = tid & 63;
    const int quad = lane >> 4, l15 = lane & 15;
    const int wm2 = w >> 1, wn2 = w & 1;

    floatx4 acc[4][2];
#pragma unroll
    for (int i = 0; i < 4; i++)
#pragma unroll
        for (int j = 0; j < 2; j++) acc[i][j] = (floatx4)0.0f;

    for (int k0 = 0; k0 < 1024; k0 += 64) {
        __syncthreads();
#pragma unroll
        for (int i = 0; i < 4; i++) {
            int c = tid + i * 256;
            int row = c >> 3, ck = c & 7;
            *reinterpret_cast<uint4*>(&As[row][ck * 8]) =
                *reinterpret_cast<const uint4*>(&A[(m0 + row) * 1024 + k0 + ck * 8]);
        }
#pragma unroll
        for (int i = 0; i < 2; i++) {
            int c = tid + i * 256;
            int row = c >> 3, ck = c & 7;
            *reinterpret_cast<uint4*>(&Bs[row][ck * 8]) =
                *reinterpret_cast<const uint4*>(&W[(n0 + row) * 1024 + k0 + ck * 8]);
        }
        __syncthreads();
#pragma unroll
        for (int kk = 0; kk < 2; kk++) {
            short8 a[4], b[2];
#pragma unroll
            for (int i = 0; i < 4; i++)
                a[i] = *reinterpret_cast<const short8*>(&As[wm2 * 64 + i * 16 + l15][kk * 32 + quad * 8]);
#pragma unroll
            for (int j = 0; j < 2; j++)
                b[j] = *reinterpret_cast<const short8*>(&Bs[wn2 * 32 + j * 16 + l15][kk * 32 + quad * 8]);
#pragma unroll
            for (int mt = 0; mt < 4; mt++)
#pragma unroll
                for (int nt = 0; nt < 2; nt++)
                    acc[mt][nt] = __builtin_amdgcn_mfma_f32_16x16x32_bf16(
                        a[mt], b[nt], acc[mt][nt], 0, 0, 0);
        }
    }

#pragma unroll
    for (int nt = 0; nt < 2; nt++) {
        int col = n0 + wn2 * 32 + nt * 16 + l15;
        float bv = bias[col];
#pragma unroll
        for (int mt = 0; mt < 4; mt++) {
#pragma unroll
            for (int r = 0; r < 4; r++) {
                int row = m0 + wm2 * 64 + mt * 16 + quad * 4 + r;
                out[row * 1024 + col] = acc[mt][nt][r] + bv;
            }
        }
    }
}

extern "C" void kernel_launch(void* const* d_in, const int* in_sizes, int n_in,
                              void* d_out, int out_size, void* d_ws, size_t ws_size,
                              hipStream_t stream) {
    const float* x     = (const float*)d_in[0];
    const float* w_qkv = (const float*)d_in[1];
    const float* b_qkv = (const float*)d_in[2];
    const float* w_fc  = (const float*)d_in[3];
    const float* b_fc  = (const float*)d_in[4];
    float* out = (float*)d_out;

    const size_t M1 = 1024u * 1024u;
    short* ws = (short*)d_ws;
    // layout (shorts): Qs[0,4M) Ks[4M,8M) Vt[8M,12M) Wfb[12M,13M)
    //                  Xb[13M,17M) Wqb[17M,20M)
    //                  Opart (fp16, 8M elems) overlaps [13M,21M) -- Xb/Wqb dead
    //                  lpart (fp32, 128K) at [21M,21.25M)   total 42.5 MB
    short* Qs    = ws;
    short* Ks    = ws + 4 * M1;
    short* Vt_g  = ws + 8 * M1;
    short* Wfb   = ws + 12 * M1;
    short* Xb    = ws + 13 * M1;
    short* Wqb   = ws + 17 * M1;
    _Float16* Opart = (_Float16*)(ws + 13 * M1);
    float* lpart = (float*)(ws + 21 * M1);
    short* attnb = Qs;   // Qs dead after attn

    cvt_all<<<4096, 256, 0, stream>>>(x, w_qkv, w_fc, Xb, Wqb, Wfb);
    qkv_gemm<<<dim3(24, 32), 256, 0, stream>>>(Xb, Wqb, b_qkv, Qs, Ks, Vt_g);
    attn_kernel<<<dim3(32, 16, 2), 256, 0, stream>>>(Qs, Ks, Vt_g, Opart, lpart);
    combine_kernel<<<2048, 256, 0, stream>>>(Opart, lpart, attnb);
    fc_gemm<<<dim3(16, 32), 256, 0, stream>>>(attnb, Wfb, b_fc, out);
}